// Round 5
// baseline (2206.015 us; speedup 1.0000x reference)
//
#include <hip/hip_runtime.h>
#include <cstdint>

// ---------------------------------------------------------------------------
// TempFuseDilateAttention on MI355X — round 5: attn rewrite (anti-spill,
// SALU-uniform gather decode, DIL templated, XCD swizzle). conv/proj unchanged.
//
// Gather algebra (verified ≡ baseline kv_gather):
//   F = (cc*9+k2)*40000 + p ; p = 1600*ph + pr (64-aligned tiles, pr in [0,1600))
//   G = 25*(9*cc+k2) + ph  (wave-uniform; cc0 via readfirstlane)
//   qq = G>>4 ; rm = G&15 ; uc = qq/9 (magic 7282>>16, exact qq<1800); kk = qq-9uc
//   did = (kk/3-1)*DIL ; djd = (kk%3-1)*DIL
//   U = uc*25600 + rm*1600 + 128*did + djd          (uniform, SALU)
//   h = rm*1600 + pr (= r2) ; ok = ((h&127)+djd)u<128 && (h+128*did)u<25600
//   idx = U + pr ; value = ok ? KV[ok?idx:0] : 0
// ---------------------------------------------------------------------------

#define HWQ 40000u
#define SCALE_F 0.17677669529663687f   // 32^-0.5

// ---------------- 1x1 conv (half: 128 output channels for one head) --------
__global__ __launch_bounds__(256) void conv1x1_kernel(
    const float* __restrict__ x, const float* __restrict__ kvw,
    float* __restrict__ kvh, int ihead)
{
    __shared__ float Wt[64][132];
    __shared__ float Xt[64][132];
    const int tid = threadIdx.x;
    const int n   = blockIdx.z;
    const int oo0 = blockIdx.y * 64;
    const int p0  = blockIdx.x * 64;

    #pragma unroll
    for (int it = 0; it < 8; ++it) {
        int idx = tid + it * 256;
        int row = idx >> 5;
        int cv  = idx & 31;
        float4 wv = *(const float4*)(kvw + (size_t)(ihead * 128 + oo0 + row) * 128 + cv * 4);
        *(float4*)&Wt[row][cv * 4] = wv;
        float4 xv = *(const float4*)(x + ((size_t)n * HWQ + (size_t)(p0 + row)) * 128 + cv * 4);
        *(float4*)&Xt[row][cv * 4] = xv;
    }
    __syncthreads();

    const int ty = tid >> 4;
    const int tx = tid & 15;
    float acc[4][4];
    #pragma unroll
    for (int i = 0; i < 4; ++i)
        #pragma unroll
        for (int j = 0; j < 4; ++j) acc[i][j] = 0.0f;

    #pragma unroll
    for (int c4 = 0; c4 < 32; ++c4) {
        float4 wv[4], xv[4];
        #pragma unroll
        for (int i = 0; i < 4; ++i) wv[i] = *(float4*)&Wt[ty * 4 + i][c4 * 4];
        #pragma unroll
        for (int j = 0; j < 4; ++j) xv[j] = *(float4*)&Xt[tx + 16 * j][c4 * 4];
        #pragma unroll
        for (int i = 0; i < 4; ++i)
            #pragma unroll
            for (int j = 0; j < 4; ++j)
                acc[i][j] += wv[i].x * xv[j].x + wv[i].y * xv[j].y
                           + wv[i].z * xv[j].z + wv[i].w * xv[j].w;
    }

    #pragma unroll
    for (int i = 0; i < 4; ++i)
        #pragma unroll
        for (int j = 0; j < 4; ++j)
            kvh[((size_t)n * 128 + (size_t)(oo0 + ty * 4 + i)) * HWQ + (size_t)(p0 + tx + 16 * j)]
                = acc[i][j];
}

// ---------------- attention (templated on dilation) -------------------------
template<int DIL>
__global__ __launch_bounds__(256, 4) void attn_t(
    const float* __restrict__ Qin, const float* __restrict__ KVh,
    float* __restrict__ Qout)
{
    // XCD-chunked bijective swizzle (nwg=1250, 8 XCDs: q=156, r=2 -> m204)
    uint32_t g0  = blockIdx.x;
    uint32_t xcd = g0 & 7u, loc = g0 >> 3u;
    uint32_t wg  = (xcd < 2u ? xcd * 157u : 314u + (xcd - 2u) * 156u) + loc;
    uint32_t b   = wg / 625u;
    uint32_t t   = wg - b * 625u;
    uint32_t ph  = t / 25u;                 // p-high digit (0..24)
    uint32_t pr0 = (t - ph * 25u) << 6u;    // 64-aligned within 1600

    const uint32_t pl  = threadIdx.x & 63u;
    const uint32_t nh  = __builtin_amdgcn_readfirstlane(threadIdx.x >> 6u);
    const uint32_t cc0 = nh << 5u;          // wave-uniform (SGPR)
    const uint32_t pr  = pr0 + pl;
    const uint32_t p   = ph * 1600u + pr;

    const float* __restrict__ Qb = Qin + (size_t)b * 5120000u;
    const float* __restrict__ Kb = KVh + (size_t)(2u * b) * 5120000u;
    const float* __restrict__ Vb = KVh + (size_t)(2u * b + 1u) * 5120000u;

    const uint32_t Gbase = 225u * cc0 + ph;

    // ---- QK^T: s[k2] = sum_j q_j * K[...]  (q streamed, not kept) ----------
    float s[9];
    #pragma unroll
    for (int k = 0; k < 9; ++k) s[k] = 0.0f;

    #pragma unroll
    for (int j = 0; j < 32; ++j) {
        float qj = Qb[(size_t)(cc0 + (uint32_t)j) * HWQ + p];
        #pragma unroll
        for (int k2 = 0; k2 < 9; ++k2) {
            const uint32_t Gc = Gbase + 25u * (9u * (uint32_t)j + (uint32_t)k2);
            uint32_t qq = Gc >> 4u, rm = Gc & 15u;         // uniform
            uint32_t uc = (qq * 7282u) >> 16u;             // qq/9 exact (<1800)
            uint32_t kk = qq - uc * 9u;
            uint32_t ik = (kk * 11u) >> 5u;                // kk/3
            int did = ((int)ik - 1) * DIL;
            int djd = ((int)(kk - ik * 3u) - 1) * DIL;
            int U   = (int)(uc * 25600u + rm * 1600u) + did * 128 + djd;
            uint32_t h = rm * 1600u + pr;                  // per-lane (1 VALU)
            bool ok = ((uint32_t)((int)(h & 127u) + djd) < 128u) &&
                      ((uint32_t)((int)h + did * 128) < 25600u);
            uint32_t addr = ok ? (uint32_t)((int)pr + U) : 0u;
            float v = Kb[addr];
            v = ok ? v : 0.0f;
            s[k2] = fmaf(qj, v, s[k2]);
        }
    }

    // ---- softmax over 9 (scale folded into exp) ----------------------------
    float m = s[0];
    #pragma unroll
    for (int k = 1; k < 9; ++k) m = fmaxf(m, s[k]);
    float a[9];
    float sum = 0.0f;
    #pragma unroll
    for (int k = 0; k < 9; ++k) {
        a[k] = __expf((s[k] - m) * SCALE_F);
        sum += a[k];
    }
    const float inv = 1.0f / sum;

    // ---- PV: out[hd] = inv * sum_k2 a[k2] * V[...]  (hd in groups of 4) ----
    float* dst = Qout + (size_t)b * 5120000u + (size_t)p * 128u + cc0;
    #pragma unroll
    for (int h4 = 0; h4 < 8; ++h4) {
        float ov[4];
        #pragma unroll
        for (int q4 = 0; q4 < 4; ++q4) {
            const uint32_t hd = (uint32_t)(h4 * 4 + q4);
            float acc = 0.0f;
            #pragma unroll
            for (int k2 = 0; k2 < 9; ++k2) {
                const uint32_t Gc = Gbase + 25u * (9u * hd + (uint32_t)k2);
                uint32_t qq = Gc >> 4u, rm = Gc & 15u;
                uint32_t uc = (qq * 7282u) >> 16u;
                uint32_t kk = qq - uc * 9u;
                uint32_t ik = (kk * 11u) >> 5u;
                int did = ((int)ik - 1) * DIL;
                int djd = ((int)(kk - ik * 3u) - 1) * DIL;
                int U   = (int)(uc * 25600u + rm * 1600u) + did * 128 + djd;
                uint32_t h = rm * 1600u + pr;
                bool ok = ((uint32_t)((int)(h & 127u) + djd) < 128u) &&
                          ((uint32_t)((int)h + did * 128) < 25600u);
                uint32_t addr = ok ? (uint32_t)((int)pr + U) : 0u;
                float v = Vb[addr];
                v = ok ? v : 0.0f;
                acc = fmaf(a[k2], v, acc);
            }
            ov[q4] = acc * inv;
        }
        *(float4*)(dst + h4 * 4) = make_float4(ov[0], ov[1], ov[2], ov[3]);
    }
}

// ---------------- final projection (in-place safe) --------------------------
__global__ __launch_bounds__(256) void proj_kernel(
    const float* qin, const float* __restrict__ pw,
    const float* __restrict__ pb, float* outp)
{
    __shared__ float Xt[64][132];
    __shared__ float bias[128];
    const int tid = threadIdx.x;
    const int b   = blockIdx.y;
    const int p0  = blockIdx.x * 64;
    const size_t base = (size_t)b * 5120000u + (size_t)p0 * 128u;

    #pragma unroll
    for (int it = 0; it < 8; ++it) {
        int idx = tid + it * 256;
        int row = idx >> 5;
        int cv  = idx & 31;
        float4 v = *(const float4*)(qin + base + (size_t)row * 128 + cv * 4);
        *(float4*)&Xt[row][cv * 4] = v;
    }
    if (tid < 32) {
        float4 tv = *(const float4*)(pb + tid * 4);
        *(float4*)&bias[tid * 4] = tv;
    }
    __syncthreads();

    const int ty = tid >> 4;
    const int tx = tid & 15;
    float acc[8][4];
    #pragma unroll
    for (int i = 0; i < 8; ++i)
        #pragma unroll
        for (int j = 0; j < 4; ++j) acc[i][j] = 0.0f;

    #pragma unroll
    for (int c4 = 0; c4 < 32; ++c4) {
        float4 xv[4], wv[8];
        #pragma unroll
        for (int j = 0; j < 4; ++j) xv[j] = *(float4*)&Xt[tx + 16 * j][c4 * 4];
        #pragma unroll
        for (int i = 0; i < 8; ++i)
            wv[i] = *(const float4*)(pw + (size_t)(ty * 8 + i) * 128 + c4 * 4);
        #pragma unroll
        for (int i = 0; i < 8; ++i)
            #pragma unroll
            for (int j = 0; j < 4; ++j)
                acc[i][j] += wv[i].x * xv[j].x + wv[i].y * xv[j].y
                           + wv[i].z * xv[j].z + wv[i].w * xv[j].w;
    }

    #pragma unroll
    for (int j = 0; j < 4; ++j) {
        float* drow = outp + base + (size_t)(tx + 16 * j) * 128 + ty * 8;
        float4 lo = make_float4(acc[0][j] + bias[ty * 8 + 0], acc[1][j] + bias[ty * 8 + 1],
                                acc[2][j] + bias[ty * 8 + 2], acc[3][j] + bias[ty * 8 + 3]);
        float4 hi = make_float4(acc[4][j] + bias[ty * 8 + 4], acc[5][j] + bias[ty * 8 + 5],
                                acc[6][j] + bias[ty * 8 + 6], acc[7][j] + bias[ty * 8 + 7]);
        *(float4*)(drow)     = lo;
        *(float4*)(drow + 4) = hi;
    }
}

// ---------------------------------------------------------------------------
extern "C" void kernel_launch(void* const* d_in, const int* in_sizes, int n_in,
                              void* d_out, int out_size, void* d_ws, size_t ws_size,
                              hipStream_t stream)
{
    const float* q   = (const float*)d_in[0];
    const float* x   = (const float*)d_in[1];
    const float* kvw = (const float*)d_in[2];
    const float* pw  = (const float*)d_in[3];
    const float* pb  = (const float*)d_in[4];
    float* out = (float*)d_out;

    const size_t KVH_BYTES = 81920000u;
    const size_t Q1_BYTES  = 40960000u;
    if (ws_size < KVH_BYTES + Q1_BYTES) return;
    float* kvh = (float*)d_ws;
    float* q1  = (float*)((char*)d_ws + KVH_BYTES);

    dim3 blk(256);
    dim3 cgrid(625, 2, 4);
    dim3 agrid(1250);
    dim3 pgrid(625, 2);

    conv1x1_kernel<<<cgrid, blk, 0, stream>>>(x, kvw, kvh, 0);
    attn_t<1>    <<<agrid, blk, 0, stream>>>(q, kvh, q1);
    conv1x1_kernel<<<cgrid, blk, 0, stream>>>(x, kvw, kvh, 1);
    attn_t<2>    <<<agrid, blk, 0, stream>>>(q1, kvh, out);
    proj_kernel  <<<pgrid, blk, 0, stream>>>(out, pw, pb, out);
}

// Round 6
// 813.912 us; speedup vs baseline: 2.7104x; 2.7104x over previous
//
#include <hip/hip_runtime.h>
#include <cstdint>

// ---------------------------------------------------------------------------
// TempFuseDilateAttention on MI355X — round 6: attn spill fix.
// r5 post-mortem: full unroll hoisted 288 decoded constants -> 1.1 GB/dispatch
// scratch round-trip (WRITE 677 MB vs 41 MB output). Fix: #pragma unroll 1 on
// outer loops + incremental Gc so the live set stays ~50 VGPR. Decode algebra
// unchanged (proven correct on-device in r5). conv/proj unchanged.
//
// Gather algebra:
//   F = (cc*9+k2)*40000 + p ; p = 1600*ph + pr ; G = 225*cc + 25*k2 + ph
//   qq = G>>4 ; rm = G&15 ; uc = qq*7282>>16 (exact /9 for qq<16000)
//   kk = qq-9uc ; did = (kk/3-1)*DIL ; djd = (kk%3-1)*DIL
//   U  = uc*25600 + rm*1600 + 128*did + djd  ; h = rm*1600+pr
//   ok = ((h&127)+djd)u<128 && (h+128*did)u<25600 ; val = ok ? KV[U+pr] : 0
// ---------------------------------------------------------------------------

#define HWQ 40000u
#define SCALE_F 0.17677669529663687f   // 32^-0.5

// ---------------- 1x1 conv (half: 128 output channels for one head) --------
__global__ __launch_bounds__(256) void conv1x1_kernel(
    const float* __restrict__ x, const float* __restrict__ kvw,
    float* __restrict__ kvh, int ihead)
{
    __shared__ float Wt[64][132];
    __shared__ float Xt[64][132];
    const int tid = threadIdx.x;
    const int n   = blockIdx.z;
    const int oo0 = blockIdx.y * 64;
    const int p0  = blockIdx.x * 64;

    #pragma unroll
    for (int it = 0; it < 8; ++it) {
        int idx = tid + it * 256;
        int row = idx >> 5;
        int cv  = idx & 31;
        float4 wv = *(const float4*)(kvw + (size_t)(ihead * 128 + oo0 + row) * 128 + cv * 4);
        *(float4*)&Wt[row][cv * 4] = wv;
        float4 xv = *(const float4*)(x + ((size_t)n * HWQ + (size_t)(p0 + row)) * 128 + cv * 4);
        *(float4*)&Xt[row][cv * 4] = xv;
    }
    __syncthreads();

    const int ty = tid >> 4;
    const int tx = tid & 15;
    float acc[4][4];
    #pragma unroll
    for (int i = 0; i < 4; ++i)
        #pragma unroll
        for (int j = 0; j < 4; ++j) acc[i][j] = 0.0f;

    #pragma unroll
    for (int c4 = 0; c4 < 32; ++c4) {
        float4 wv[4], xv[4];
        #pragma unroll
        for (int i = 0; i < 4; ++i) wv[i] = *(float4*)&Wt[ty * 4 + i][c4 * 4];
        #pragma unroll
        for (int j = 0; j < 4; ++j) xv[j] = *(float4*)&Xt[tx + 16 * j][c4 * 4];
        #pragma unroll
        for (int i = 0; i < 4; ++i)
            #pragma unroll
            for (int j = 0; j < 4; ++j)
                acc[i][j] += wv[i].x * xv[j].x + wv[i].y * xv[j].y
                           + wv[i].z * xv[j].z + wv[i].w * xv[j].w;
    }

    #pragma unroll
    for (int i = 0; i < 4; ++i)
        #pragma unroll
        for (int j = 0; j < 4; ++j)
            kvh[((size_t)n * 128 + (size_t)(oo0 + ty * 4 + i)) * HWQ + (size_t)(p0 + tx + 16 * j)]
                = acc[i][j];
}

// ---------------- per-gather decode (no hoisting: called per iteration) -----
template<int DIL>
__device__ __forceinline__ float kv_fetch(const float* __restrict__ base,
                                          uint32_t Gc, uint32_t pr)
{
    uint32_t qq = Gc >> 4u, rm = Gc & 15u;
    uint32_t uc = (qq * 7282u) >> 16u;          // qq/9 exact for qq<16000
    uint32_t kk = qq - uc * 9u;
    uint32_t ik = (kk * 11u) >> 5u;             // kk/3
    int did = ((int)ik - 1) * DIL;
    int djd = ((int)(kk - ik * 3u) - 1) * DIL;
    int U   = (int)(uc * 25600u + rm * 1600u) + did * 128 + djd;
    uint32_t h = rm * 1600u + pr;
    bool ok = ((uint32_t)((int)(h & 127u) + djd) < 128u) &&
              ((uint32_t)((int)h + did * 128) < 25600u);
    uint32_t addr = ok ? (uint32_t)((int)pr + U) : 0u;
    float v = base[addr];
    return ok ? v : 0.0f;
}

// ---------------- attention (templated on dilation) -------------------------
template<int DIL>
__global__ __launch_bounds__(256, 4) void attn_t(
    const float* __restrict__ Qin, const float* __restrict__ KVh,
    float* __restrict__ Qout)
{
    // XCD-chunked bijective swizzle (nwg=1250, 8 XCDs: q=156, r=2 -> m204)
    uint32_t g0  = blockIdx.x;
    uint32_t xcd = g0 & 7u, loc = g0 >> 3u;
    uint32_t wg  = (xcd < 2u ? xcd * 157u : 314u + (xcd - 2u) * 156u) + loc;
    uint32_t b   = wg / 625u;
    uint32_t t   = wg - b * 625u;
    uint32_t ph  = t / 25u;                 // p-high digit (0..24)
    uint32_t pr0 = (t - ph * 25u) << 6u;    // 64-aligned within 1600

    const uint32_t pl  = threadIdx.x & 63u;
    const uint32_t nh  = __builtin_amdgcn_readfirstlane(threadIdx.x >> 6u);
    const uint32_t cc0 = nh << 5u;          // wave-uniform (SGPR)
    const uint32_t pr  = pr0 + pl;
    const uint32_t p   = ph * 1600u + pr;

    const float* __restrict__ Qb = Qin + (size_t)b * 5120000u;
    const float* __restrict__ Kb = KVh + (size_t)(2u * b) * 5120000u;
    const float* __restrict__ Vb = KVh + (size_t)(2u * b + 1u) * 5120000u;

    const uint32_t Gbase = 225u * cc0 + ph;

    // ---- QK^T: s[k2] = sum_j q_j * K[...]  (j-loop NOT unrolled) -----------
    float s[9];
    #pragma unroll
    for (int k = 0; k < 9; ++k) s[k] = 0.0f;

    uint32_t Gj = Gbase;
    const float* qptr = Qb + (size_t)cc0 * HWQ + p;
    #pragma unroll 1
    for (int j = 0; j < 32; ++j, Gj += 225u, qptr += HWQ) {
        float qj = *qptr;
        #pragma unroll
        for (int k2 = 0; k2 < 9; ++k2) {
            float v = kv_fetch<DIL>(Kb, Gj + 25u * (uint32_t)k2, pr);
            s[k2] = fmaf(qj, v, s[k2]);
        }
    }

    // ---- softmax over 9 (scale folded into exp) ----------------------------
    float m = s[0];
    #pragma unroll
    for (int k = 1; k < 9; ++k) m = fmaxf(m, s[k]);
    float a[9];
    float sum = 0.0f;
    #pragma unroll
    for (int k = 0; k < 9; ++k) {
        a[k] = __expf((s[k] - m) * SCALE_F);
        sum += a[k];
    }
    const float inv = 1.0f / sum;

    // ---- PV: out[hd] = inv * sum_k2 a[k2]*V[...]  (h4-loop NOT unrolled) ---
    float* dst = Qout + (size_t)b * 5120000u + (size_t)p * 128u + cc0;
    uint32_t Gh = Gbase;
    #pragma unroll 1
    for (int h4 = 0; h4 < 8; ++h4, Gh += 900u) {
        float ov[4];
        #pragma unroll
        for (int q4 = 0; q4 < 4; ++q4) {
            float acc = 0.0f;
            #pragma unroll
            for (int k2 = 0; k2 < 9; ++k2) {
                float v = kv_fetch<DIL>(Vb, Gh + 225u * (uint32_t)q4 + 25u * (uint32_t)k2, pr);
                acc = fmaf(a[k2], v, acc);
            }
            ov[q4] = acc * inv;
        }
        *(float4*)(dst + h4 * 4) = make_float4(ov[0], ov[1], ov[2], ov[3]);
    }
}

// ---------------- final projection (in-place safe) --------------------------
__global__ __launch_bounds__(256) void proj_kernel(
    const float* qin, const float* __restrict__ pw,
    const float* __restrict__ pb, float* outp)
{
    __shared__ float Xt[64][132];
    __shared__ float bias[128];
    const int tid = threadIdx.x;
    const int b   = blockIdx.y;
    const int p0  = blockIdx.x * 64;
    const size_t base = (size_t)b * 5120000u + (size_t)p0 * 128u;

    #pragma unroll
    for (int it = 0; it < 8; ++it) {
        int idx = tid + it * 256;
        int row = idx >> 5;
        int cv  = idx & 31;
        float4 v = *(const float4*)(qin + base + (size_t)row * 128 + cv * 4);
        *(float4*)&Xt[row][cv * 4] = v;
    }
    if (tid < 32) {
        float4 tv = *(const float4*)(pb + tid * 4);
        *(float4*)&bias[tid * 4] = tv;
    }
    __syncthreads();

    const int ty = tid >> 4;
    const int tx = tid & 15;
    float acc[8][4];
    #pragma unroll
    for (int i = 0; i < 8; ++i)
        #pragma unroll
        for (int j = 0; j < 4; ++j) acc[i][j] = 0.0f;

    #pragma unroll
    for (int c4 = 0; c4 < 32; ++c4) {
        float4 xv[4], wv[8];
        #pragma unroll
        for (int j = 0; j < 4; ++j) xv[j] = *(float4*)&Xt[tx + 16 * j][c4 * 4];
        #pragma unroll
        for (int i = 0; i < 8; ++i)
            wv[i] = *(const float4*)(pw + (size_t)(ty * 8 + i) * 128 + c4 * 4);
        #pragma unroll
        for (int i = 0; i < 8; ++i)
            #pragma unroll
            for (int j = 0; j < 4; ++j)
                acc[i][j] += wv[i].x * xv[j].x + wv[i].y * xv[j].y
                           + wv[i].z * xv[j].z + wv[i].w * xv[j].w;
    }

    #pragma unroll
    for (int j = 0; j < 4; ++j) {
        float* drow = outp + base + (size_t)(tx + 16 * j) * 128 + ty * 8;
        float4 lo = make_float4(acc[0][j] + bias[ty * 8 + 0], acc[1][j] + bias[ty * 8 + 1],
                                acc[2][j] + bias[ty * 8 + 2], acc[3][j] + bias[ty * 8 + 3]);
        float4 hi = make_float4(acc[4][j] + bias[ty * 8 + 4], acc[5][j] + bias[ty * 8 + 5],
                                acc[6][j] + bias[ty * 8 + 6], acc[7][j] + bias[ty * 8 + 7]);
        *(float4*)(drow)     = lo;
        *(float4*)(drow + 4) = hi;
    }
}

// ---------------------------------------------------------------------------
extern "C" void kernel_launch(void* const* d_in, const int* in_sizes, int n_in,
                              void* d_out, int out_size, void* d_ws, size_t ws_size,
                              hipStream_t stream)
{
    const float* q   = (const float*)d_in[0];
    const float* x   = (const float*)d_in[1];
    const float* kvw = (const float*)d_in[2];
    const float* pw  = (const float*)d_in[3];
    const float* pb  = (const float*)d_in[4];
    float* out = (float*)d_out;

    const size_t KVH_BYTES = 81920000u;
    const size_t Q1_BYTES  = 40960000u;
    if (ws_size < KVH_BYTES + Q1_BYTES) return;
    float* kvh = (float*)d_ws;
    float* q1  = (float*)((char*)d_ws + KVH_BYTES);

    dim3 blk(256);
    dim3 cgrid(625, 2, 4);
    dim3 agrid(1250);
    dim3 pgrid(625, 2);

    conv1x1_kernel<<<cgrid, blk, 0, stream>>>(x, kvw, kvh, 0);
    attn_t<1>    <<<agrid, blk, 0, stream>>>(q, kvh, q1);
    conv1x1_kernel<<<cgrid, blk, 0, stream>>>(x, kvw, kvh, 1);
    attn_t<2>    <<<agrid, blk, 0, stream>>>(q1, kvh, out);
    proj_kernel  <<<pgrid, blk, 0, stream>>>(out, pw, pb, out);
}